// Round 1
// baseline (2733.559 us; speedup 1.0000x reference)
//
#include <hip/hip_runtime.h>
#include <stdint.h>

#define EPS 1e-5f

// ---------------------------------------------------------------------------
// conv1: full-precision 3->384 conv, 3x3 pad 1, on 128x3x32x32, fused BN+sign,
// output bit-packed along output channel: s1[n][y][cog(12)][x], bit = co_sub.
// block = 384 threads (x:32 lanes fast, cog:12), grid = 128*32 (n,y)
// ---------------------------------------------------------------------------
__global__ void conv1_pack_kernel(const float* __restrict__ x,
                                  const float* __restrict__ w1,
                                  const float* __restrict__ g,
                                  const float* __restrict__ b,
                                  const float* __restrict__ m,
                                  const float* __restrict__ v,
                                  uint32_t* __restrict__ out)
{
    int bid = blockIdx.x;
    int n = bid >> 5;
    int y = bid & 31;
    int tid = threadIdx.x;
    int xo = tid & 31;
    int cog = tid >> 5;   // 0..11

    float a[27];
#pragma unroll
    for (int ci = 0; ci < 3; ++ci)
#pragma unroll
        for (int dy = 0; dy < 3; ++dy)
#pragma unroll
            for (int dx = 0; dx < 3; ++dx) {
                int yy = y + dy - 1, xx = xo + dx - 1;
                float val = 0.f;
                if (yy >= 0 && yy < 32 && xx >= 0 && xx < 32)
                    val = x[((n * 3 + ci) * 32 + yy) * 32 + xx];
                a[(ci * 3 + dy) * 3 + dx] = val;
            }

    uint32_t word = 0;
    for (int cs = 0; cs < 32; ++cs) {
        int co = cog * 32 + cs;
        const float* wp = w1 + co * 27;
        float acc = 0.f;
#pragma unroll
        for (int i = 0; i < 27; ++i) acc += a[i] * wp[i];
        float t = (acc - m[co]) * (g[co] * rsqrtf(v[co] + EPS)) + b[co];
        word |= (uint32_t)(t >= 0.f) << cs;
    }
    out[((n * 32 + y) * 12 + cog) * 32 + xo] = word;
}

// ---------------------------------------------------------------------------
// binarize + bit-pack weights (OIHW, Ci multiple of 32).
// layout: pw[cog][tap][cw][co_sub]  (co_sub contiguous -> dwordx4 loads)
// ---------------------------------------------------------------------------
__global__ void pack_w_kernel(const float* __restrict__ w,
                              uint32_t* __restrict__ out,
                              int Co, int Ci)
{
    int CW = Ci >> 5;
    int idx = blockIdx.x * 256 + threadIdx.x;
    int total = Co * 9 * CW;
    if (idx >= total) return;
    int cs  = idx & 31;
    int cw  = (idx >> 5) % CW;
    int tap = (idx / (32 * CW)) % 9;
    int cog = idx / (32 * CW * 9);
    int co = cog * 32 + cs;
    uint32_t word = 0;
    for (int bit = 0; bit < 32; ++bit) {
        int ci = cw * 32 + bit;
        float wv = w[(long)co * Ci * 9 + ci * 9 + tap];
        word |= (uint32_t)(wv >= 0.f) << bit;
    }
    out[idx] = word;
}

// ---------------------------------------------------------------------------
// binary conv 3x3 pad 1 (+ optional 2x2 maxpool) + BN + (sign-pack | hardtanh)
// act layout:  [N][Hin][CWIN][Win]  (uint32 words, bit = ci_sub)
// wgt layout:  [cog][tap][cw][32]   (co_sub contiguous)
// aout layout: [N][Ho][CWo][Wo]     (bit = co_sub)      (if !OUTF32)
// fout layout: [N][Co][Ho][Wo]      fp32 hardtanh value (if OUTF32)
// thread = one (n, cog, yo, xo): computes all 32 co of one output word.
// ---------------------------------------------------------------------------
template<int CWIN, bool POOL, bool OUTF32>
__global__ void bconv_kernel(const uint32_t* __restrict__ act,
                             const uint32_t* __restrict__ wgt,
                             const float* __restrict__ g,
                             const float* __restrict__ b,
                             const float* __restrict__ m,
                             const float* __restrict__ v,
                             uint32_t* __restrict__ aout,
                             float* __restrict__ fout,
                             int N, int Hin, int Win, int Co)
{
    constexpr int PX = POOL ? 4 : 1;
    const int Ho = POOL ? (Hin >> 1) : Hin;
    const int Wo = POOL ? (Win >> 1) : Win;
    const int CWo = Co >> 5;

    int gid = blockIdx.x * blockDim.x + threadIdx.x;
    int total = N * CWo * Ho * Wo;
    if (gid >= total) return;
    int xo  = gid % Wo;
    int yo  = (gid / Wo) % Ho;
    int cog = (gid / (Wo * Ho)) % CWo;
    int n   = gid / (Wo * Ho * CWo);

    int py0 = POOL ? (2 * yo) : yo;
    int px0 = POOL ? (2 * xo) : xo;

    // analytic valid-tap count per pooled sub-pixel (padding contributes 0)
    int nv[PX];
#pragma unroll
    for (int p = 0; p < PX; ++p) {
        int py = py0 + (POOL ? (p >> 1) : 0);
        int px = px0 + (POOL ? (p & 1) : 0);
        int vy = 3 - (py == 0) - (py == Hin - 1);
        int vx = 3 - (px == 0) - (px == Win - 1);
        nv[p] = vy * vx;
    }

    uint32_t word = 0;

    for (int chunk = 0; chunk < 2; ++chunk) {
        int cnt[PX][16];
#pragma unroll
        for (int p = 0; p < PX; ++p)
#pragma unroll
            for (int i = 0; i < 16; ++i) cnt[p][i] = 0;

        for (int tap = 0; tap < 9; ++tap) {
            int dy = tap / 3, dx = tap % 3;
            int yy[PX], xx[PX];
            bool val[PX];
#pragma unroll
            for (int p = 0; p < PX; ++p) {
                int py = py0 + (POOL ? (p >> 1) : 0);
                int px = px0 + (POOL ? (p & 1) : 0);
                yy[p] = py + dy - 1;
                xx[p] = px + dx - 1;
                val[p] = (yy[p] >= 0) && (yy[p] < Hin) && (xx[p] >= 0) && (xx[p] < Win);
            }
            const uint32_t* wtap = wgt + ((cog * 9 + tap) * CWIN) * 32 + chunk * 16;
            for (int cw = 0; cw < CWIN; ++cw) {
                const uint4* wp4 = reinterpret_cast<const uint4*>(wtap + cw * 32);
                uint4 wa = wp4[0], wb = wp4[1], wc = wp4[2], wd = wp4[3];
                uint32_t wv[16] = { wa.x, wa.y, wa.z, wa.w,
                                    wb.x, wb.y, wb.z, wb.w,
                                    wc.x, wc.y, wc.z, wc.w,
                                    wd.x, wd.y, wd.z, wd.w };
#pragma unroll
                for (int p = 0; p < PX; ++p) {
                    if (val[p]) {
                        uint32_t av = act[((n * Hin + yy[p]) * CWIN + cw) * Win + xx[p]];
#pragma unroll
                        for (int i = 0; i < 16; ++i)
                            cnt[p][i] += __popc(av ^ wv[i]);
                    }
                }
            }
        }

#pragma unroll
        for (int i = 0; i < 16; ++i) {
            int co = cog * 32 + chunk * 16 + i;
            int best = 32 * CWIN * nv[0] - 2 * cnt[0][i];
            if (POOL) {
#pragma unroll
                for (int p = 1; p < PX; ++p) {
                    int d = 32 * CWIN * nv[p] - 2 * cnt[p][i];
                    best = max(best, d);
                }
            }
            float t = ((float)best - m[co]) * (g[co] * rsqrtf(v[co] + EPS)) + b[co];
            if (OUTF32) {
                float ht = fminf(1.f, fmaxf(-1.f, t));
                fout[((n * Co + co) * Ho + yo) * Wo + xo] = ht;
            } else {
                word |= (uint32_t)(t >= 0.f) << (chunk * 16 + i);
            }
        }
    }

    if (!OUTF32)
        aout[((n * Ho + yo) * CWo + cog) * Wo + xo] = word;
}

// ---------------------------------------------------------------------------
// classifier: logits = h @ w_lin.T  (128 x 8192 x 10) then log_softmax
// one block (256 threads) per sample n
// ---------------------------------------------------------------------------
__global__ void classifier_kernel(const float* __restrict__ h,
                                  const float* __restrict__ wl,
                                  float* __restrict__ out)
{
    int n = blockIdx.x;
    int tid = threadIdx.x;
    float acc[10];
#pragma unroll
    for (int j = 0; j < 10; ++j) acc[j] = 0.f;
    for (int k = tid; k < 8192; k += 256) {
        float hv = h[n * 8192 + k];
#pragma unroll
        for (int j = 0; j < 10; ++j) acc[j] += hv * wl[j * 8192 + k];
    }
    __shared__ float sred[256];
    __shared__ float logit[10];
    for (int j = 0; j < 10; ++j) {
        sred[tid] = acc[j];
        __syncthreads();
        for (int s = 128; s > 0; s >>= 1) {
            if (tid < s) sred[tid] += sred[tid + s];
            __syncthreads();
        }
        if (tid == 0) logit[j] = sred[0];
        __syncthreads();
    }
    if (tid == 0) {
        float mx = logit[0];
#pragma unroll
        for (int j = 1; j < 10; ++j) mx = fmaxf(mx, logit[j]);
        float s = 0.f;
#pragma unroll
        for (int j = 0; j < 10; ++j) s += expf(logit[j] - mx);
        float lse = logf(s) + mx;
#pragma unroll
        for (int j = 0; j < 10; ++j) out[n * 10 + j] = logit[j] - lse;
    }
}

// ---------------------------------------------------------------------------
extern "C" void kernel_launch(void* const* d_in, const int* in_sizes, int n_in,
                              void* d_out, int out_size, void* d_ws, size_t ws_size,
                              hipStream_t stream)
{
    const float* x    = (const float*)d_in[0];
    const float* w1   = (const float*)d_in[1];
    const float* w2   = (const float*)d_in[2];
    const float* w3   = (const float*)d_in[3];
    const float* w4   = (const float*)d_in[4];
    const float* w5   = (const float*)d_in[5];
    const float* w6   = (const float*)d_in[6];
    const float* bn_g[6], *bn_b[6], *bn_m[6], *bn_v[6];
    for (int i = 0; i < 6; ++i) {
        bn_g[i] = (const float*)d_in[7 + i * 4 + 0];
        bn_b[i] = (const float*)d_in[7 + i * 4 + 1];
        bn_m[i] = (const float*)d_in[7 + i * 4 + 2];
        bn_v[i] = (const float*)d_in[7 + i * 4 + 3];
    }
    const float* wlin = (const float*)d_in[31];
    float* out = (float*)d_out;

    // workspace carve-up (all fully written before read; ~21 MB total)
    char* ws = (char*)d_ws;
    auto alloc = [&](size_t bytes) {
        char* p = ws;
        ws += (bytes + 255) & ~(size_t)255;
        return p;
    };
    uint32_t* pw2 = (uint32_t*)alloc((size_t)384 * 9 * 12 * 4);
    uint32_t* pw3 = (uint32_t*)alloc((size_t)768 * 9 * 12 * 4);
    uint32_t* pw4 = (uint32_t*)alloc((size_t)768 * 9 * 24 * 4);
    uint32_t* pw5 = (uint32_t*)alloc((size_t)1536 * 9 * 24 * 4);
    uint32_t* pw6 = (uint32_t*)alloc((size_t)512 * 9 * 48 * 4);
    uint32_t* s1 = (uint32_t*)alloc((size_t)128 * 32 * 12 * 32 * 4);
    uint32_t* s2 = (uint32_t*)alloc((size_t)128 * 16 * 12 * 16 * 4);
    uint32_t* s3 = (uint32_t*)alloc((size_t)128 * 16 * 24 * 16 * 4);
    uint32_t* s4 = (uint32_t*)alloc((size_t)128 * 8 * 24 * 8 * 4);
    uint32_t* s5 = (uint32_t*)alloc((size_t)128 * 8 * 48 * 8 * 4);
    float*    h6 = (float*)alloc((size_t)128 * 512 * 16 * 4);

    // pack binarized weights
    {
        int t2 = 384 * 9 * 12, t3 = 768 * 9 * 12, t4 = 768 * 9 * 24,
            t5 = 1536 * 9 * 24, t6 = 512 * 9 * 48;
        pack_w_kernel<<<(t2 + 255) / 256, 256, 0, stream>>>(w2, pw2, 384, 384);
        pack_w_kernel<<<(t3 + 255) / 256, 256, 0, stream>>>(w3, pw3, 768, 384);
        pack_w_kernel<<<(t4 + 255) / 256, 256, 0, stream>>>(w4, pw4, 768, 768);
        pack_w_kernel<<<(t5 + 255) / 256, 256, 0, stream>>>(w5, pw5, 1536, 768);
        pack_w_kernel<<<(t6 + 255) / 256, 256, 0, stream>>>(w6, pw6, 512, 1536);
    }

    // block 1: fp32 conv + BN + sign-pack
    conv1_pack_kernel<<<128 * 32, 384, 0, stream>>>(
        x, w1, bn_g[0], bn_b[0], bn_m[0], bn_v[0], s1);

    // block 2: binary conv 384->384 @32x32 + pool + BN + sign
    {
        int total = 128 * 12 * 16 * 16;
        bconv_kernel<12, true, false><<<(total + 255) / 256, 256, 0, stream>>>(
            s1, pw2, bn_g[1], bn_b[1], bn_m[1], bn_v[1], s2, nullptr, 128, 32, 32, 384);
    }
    // block 3: binary conv 384->768 @16x16 + BN + sign
    {
        int total = 128 * 24 * 16 * 16;
        bconv_kernel<12, false, false><<<(total + 255) / 256, 256, 0, stream>>>(
            s2, pw3, bn_g[2], bn_b[2], bn_m[2], bn_v[2], s3, nullptr, 128, 16, 16, 768);
    }
    // block 4: binary conv 768->768 @16x16 + pool + BN + sign
    {
        int total = 128 * 24 * 8 * 8;
        bconv_kernel<24, true, false><<<(total + 255) / 256, 256, 0, stream>>>(
            s3, pw4, bn_g[3], bn_b[3], bn_m[3], bn_v[3], s4, nullptr, 128, 16, 16, 768);
    }
    // block 5: binary conv 768->1536 @8x8 + BN + sign
    {
        int total = 128 * 48 * 8 * 8;
        bconv_kernel<24, false, false><<<(total + 255) / 256, 256, 0, stream>>>(
            s4, pw5, bn_g[4], bn_b[4], bn_m[4], bn_v[4], s5, nullptr, 128, 8, 8, 1536);
    }
    // block 6: binary conv 1536->512 @8x8 + pool + BN + hardtanh (fp32 out, NCHW)
    {
        int total = 128 * 16 * 4 * 4;
        bconv_kernel<48, true, true><<<(total + 255) / 256, 256, 0, stream>>>(
            s5, pw6, bn_g[5], bn_b[5], bn_m[5], bn_v[5], nullptr, h6, 128, 8, 8, 512);
    }

    // classifier + log_softmax
    classifier_kernel<<<128, 256, 0, stream>>>(h6, wlin, out);
}

// Round 2
// 1682.980 us; speedup vs baseline: 1.6242x; 1.6242x over previous
//
#include <hip/hip_runtime.h>
#include <stdint.h>

#define EPS 1e-5f

// ---------------------------------------------------------------------------
// conv1: full-precision 3->384 conv, 3x3 pad 1, fused BN+sign, bit-packed out
// s1[n][y][cog(12)][x], bit = co&31.  block=384 (x:32, cog:12), grid=128*32
// ---------------------------------------------------------------------------
__global__ void conv1_pack_kernel(const float* __restrict__ x,
                                  const float* __restrict__ w1,
                                  const float* __restrict__ g,
                                  const float* __restrict__ b,
                                  const float* __restrict__ m,
                                  const float* __restrict__ v,
                                  uint32_t* __restrict__ out)
{
    int bid = blockIdx.x;
    int n = bid >> 5;
    int y = bid & 31;
    int tid = threadIdx.x;
    int xo = tid & 31;
    int cog = tid >> 5;   // 0..11

    float a[27];
#pragma unroll
    for (int ci = 0; ci < 3; ++ci)
#pragma unroll
        for (int dy = 0; dy < 3; ++dy)
#pragma unroll
            for (int dx = 0; dx < 3; ++dx) {
                int yy = y + dy - 1, xx = xo + dx - 1;
                float val = 0.f;
                if (yy >= 0 && yy < 32 && xx >= 0 && xx < 32)
                    val = x[((n * 3 + ci) * 32 + yy) * 32 + xx];
                a[(ci * 3 + dy) * 3 + dx] = val;
            }

    uint32_t word = 0;
    for (int cs = 0; cs < 32; ++cs) {
        int co = cog * 32 + cs;
        const float* wp = w1 + co * 27;
        float acc = 0.f;
#pragma unroll
        for (int i = 0; i < 27; ++i) acc += a[i] * wp[i];
        float t = (acc - m[co]) * (g[co] * rsqrtf(v[co] + EPS)) + b[co];
        word |= (uint32_t)(t >= 0.f) << cs;
    }
    out[((n * 32 + y) * 12 + cog) * 32 + xo] = word;
}

// ---------------------------------------------------------------------------
// binarize + bit-pack weights: out[(tap*CW + cw)*Co + co], bit = ci&31
// ---------------------------------------------------------------------------
__global__ void pack_w2_kernel(const float* __restrict__ w,
                               uint32_t* __restrict__ out,
                               int Co, int Ci)
{
    int CW = Ci >> 5;
    int idx = blockIdx.x * 256 + threadIdx.x;
    int total = 9 * CW * Co;
    if (idx >= total) return;
    int co  = idx % Co;
    int cw  = (idx / Co) % CW;
    int tap = idx / (Co * CW);
    uint32_t word = 0;
    for (int bit = 0; bit < 32; ++bit) {
        float wv = w[(long)co * Ci * 9 + (cw * 32 + bit) * 9 + tap];
        word |= (uint32_t)(wv >= 0.f) << bit;
    }
    out[idx] = word;
}

// wpop[tap*Co + co] = sum_cw popc(w) — for zero-pad boundary correction
__global__ void wpop_kernel(const uint32_t* __restrict__ pw,
                            int* __restrict__ wpop, int Co, int CW)
{
    int idx = blockIdx.x * 256 + threadIdx.x;
    if (idx >= 9 * Co) return;
    int co = idx % Co, tap = idx / Co;
    int s = 0;
    for (int cw = 0; cw < CW; ++cw) s += __popc(pw[(tap * CW + cw) * Co + co]);
    wpop[idx] = s;
}

// ---------------------------------------------------------------------------
// bconv2: binary conv 3x3 pad1 (+opt 2x2 maxpool) + BN + (sign-pack|hardtanh)
// thread = one output channel; block = COB channels for one (n, yo) out row.
// act:  [N][Hin][CWIN][Win] packed words (bit = ci&31), staged in LDS w/ halo
// wgt:  [9][CWIN][Co] (co fastest -> coalesced per-lane loads)
// aout: [N][Ho][CWo][Wo] (bit = co&31) via __ballot
// fout: [N][Co][Ho][Wo] fp32 hardtanh
// ---------------------------------------------------------------------------
template<int CWIN, int WIN, bool POOL, bool OUTF32, int COB, int XT>
__global__ __launch_bounds__(COB) void bconv2_kernel(
    const uint32_t* __restrict__ act,
    const uint32_t* __restrict__ wgt,
    const int* __restrict__ wpop,
    const float* __restrict__ g, const float* __restrict__ b,
    const float* __restrict__ m, const float* __restrict__ v,
    uint32_t* __restrict__ aout, float* __restrict__ fout,
    int N, int Co)
{
    constexpr int HIN = WIN;
    constexpr int HO = POOL ? WIN / 2 : WIN;
    constexpr int WO = HO;
    constexpr int ROWS = POOL ? 4 : 3;
    constexpr int LW = WIN + 2;
    constexpr int PSUB = POOL ? 2 : 1;   // subpixel rows/cols per output pixel
    constexpr int NC = XT * PSUB;        // accumulator columns (input cols)
    constexpr int SPAN = NC + 2;

    __shared__ uint32_t lds[ROWS][CWIN][LW];

    const int cbn = Co / COB;
    int bid = blockIdx.x;
    int cb = bid % cbn;
    int yo = (bid / cbn) % HO;
    int n  = bid / (cbn * HO);
    int tid = threadIdx.x;

    // stage act rows (zero-padded halo)
    {
        int total = ROWS * CWIN * LW;
        int y0 = POOL ? (2 * yo - 1) : (yo - 1);
        for (int idx = tid; idx < total; idx += COB) {
            int xp = idx % LW;
            int cw = (idx / LW) % CWIN;
            int r  = idx / (LW * CWIN);
            int xg = xp - 1;
            int yg = y0 + r;
            uint32_t val = 0;
            if (xg >= 0 && xg < WIN && yg >= 0 && yg < HIN)
                val = act[((n * HIN + yg) * CWIN + cw) * WIN + xg];
            (&lds[0][0][0])[idx] = val;
        }
    }
    __syncthreads();

    int co = cb * COB + tid;
    float scale = g[co] * rsqrtf(v[co] + EPS);
    float mean = m[co], beta = b[co];

    int wp9[9];
#pragma unroll
    for (int t9 = 0; t9 < 9; ++t9) wp9[t9] = wpop[t9 * Co + co];

    int py0 = POOL ? 2 * yo : yo;
    bool rowlo = (py0 == 0);
    bool rowhi = (py0 + PSUB - 1 == HIN - 1);

    for (int xo0 = 0; xo0 < WO; xo0 += XT) {
        int cnt[PSUB][NC];
#pragma unroll
        for (int p = 0; p < PSUB; ++p)
#pragma unroll
            for (int c = 0; c < NC; ++c) cnt[p][c] = 0;

        int xb = xo0 * PSUB;   // lds col base (col j == input x j-1 ... halo)

        for (int cw = 0; cw < CWIN; ++cw) {
            uint32_t wv[9];
#pragma unroll
            for (int t9 = 0; t9 < 9; ++t9)
                wv[t9] = wgt[(t9 * CWIN + cw) * Co + co];
#pragma unroll
            for (int r = 0; r < ROWS; ++r) {
                uint32_t aw[SPAN];
#pragma unroll
                for (int j = 0; j < SPAN; ++j) aw[j] = lds[r][cw][xb + j];
#pragma unroll
                for (int p = 0; p < PSUB; ++p) {
                    int dy = r - p;
                    if (dy < 0 || dy > 2) continue;
#pragma unroll
                    for (int dx = 0; dx < 3; ++dx) {
                        uint32_t w = wv[dy * 3 + dx];
#pragma unroll
                        for (int c = 0; c < NC; ++c)
                            cnt[p][c] += __popc(aw[c + dx] ^ w);
                    }
                }
            }
        }

        // epilogue: dot = 9*32*CWIN - 2*cnt - boundary corr; pool-max; BN
#pragma unroll
        for (int q = 0; q < XT; ++q) {
            int xo = xo0 + q;
            float best = -1e30f;
            constexpr int base9 = 9 * 32 * CWIN;
#pragma unroll
            for (int p = 0; p < PSUB; ++p)
#pragma unroll
                for (int cc = 0; cc < PSUB; ++cc) {
                    int c = q * PSUB + cc;
                    int px = xb + c;         // absolute input col
                    int dot = base9 - 2 * cnt[p][c];
                    bool plo = rowlo && (p == 0);
                    bool phi = rowhi && (p == PSUB - 1);
                    bool clo = (px == 0);
                    bool chi = (px == WIN - 1);
                    if (plo | phi | clo | chi) {
#pragma unroll
                        for (int dy = 0; dy < 3; ++dy)
#pragma unroll
                            for (int dx = 0; dx < 3; ++dx) {
                                bool inv = (dy == 0 && plo) || (dy == 2 && phi)
                                        || (dx == 0 && clo) || (dx == 2 && chi);
                                if (inv) dot -= 32 * CWIN - 2 * wp9[dy * 3 + dx];
                            }
                    }
                    float fv = (float)dot;
                    best = fmaxf(best, fv);
                }
            float t = (best - mean) * scale + beta;
            if (OUTF32) {
                float ht = fminf(1.f, fmaxf(-1.f, t));
                fout[(((long)n * Co + co) * HO + yo) * WO + xo] = ht;
            } else {
                unsigned long long mask = __ballot(t >= 0.f);
                int lane = tid & 63;
                if ((lane & 31) == 0) {
                    uint32_t wrd = (uint32_t)(mask >> (lane & 32));
                    int cog = co >> 5;
                    aout[((n * HO + yo) * (Co >> 5) + cog) * WO + xo] = wrd;
                }
            }
        }
    }
}

// ---------------------------------------------------------------------------
// classifier: logits = h @ w_lin.T (128 x 8192 x 10) then log_softmax
// ---------------------------------------------------------------------------
__global__ void classifier_kernel(const float* __restrict__ h,
                                  const float* __restrict__ wl,
                                  float* __restrict__ out)
{
    int n = blockIdx.x;
    int tid = threadIdx.x;
    float acc[10];
#pragma unroll
    for (int j = 0; j < 10; ++j) acc[j] = 0.f;
    for (int k = tid; k < 8192; k += 256) {
        float hv = h[n * 8192 + k];
#pragma unroll
        for (int j = 0; j < 10; ++j) acc[j] += hv * wl[j * 8192 + k];
    }
    __shared__ float sred[256];
    __shared__ float logit[10];
    for (int j = 0; j < 10; ++j) {
        sred[tid] = acc[j];
        __syncthreads();
        for (int s = 128; s > 0; s >>= 1) {
            if (tid < s) sred[tid] += sred[tid + s];
            __syncthreads();
        }
        if (tid == 0) logit[j] = sred[0];
        __syncthreads();
    }
    if (tid == 0) {
        float mx = logit[0];
#pragma unroll
        for (int j = 1; j < 10; ++j) mx = fmaxf(mx, logit[j]);
        float s = 0.f;
#pragma unroll
        for (int j = 0; j < 10; ++j) s += expf(logit[j] - mx);
        float lse = logf(s) + mx;
#pragma unroll
        for (int j = 0; j < 10; ++j) out[n * 10 + j] = logit[j] - lse;
    }
}

// ---------------------------------------------------------------------------
extern "C" void kernel_launch(void* const* d_in, const int* in_sizes, int n_in,
                              void* d_out, int out_size, void* d_ws, size_t ws_size,
                              hipStream_t stream)
{
    const float* x    = (const float*)d_in[0];
    const float* w1   = (const float*)d_in[1];
    const float* w2   = (const float*)d_in[2];
    const float* w3   = (const float*)d_in[3];
    const float* w4   = (const float*)d_in[4];
    const float* w5   = (const float*)d_in[5];
    const float* w6   = (const float*)d_in[6];
    const float* bn_g[6], *bn_b[6], *bn_m[6], *bn_v[6];
    for (int i = 0; i < 6; ++i) {
        bn_g[i] = (const float*)d_in[7 + i * 4 + 0];
        bn_b[i] = (const float*)d_in[7 + i * 4 + 1];
        bn_m[i] = (const float*)d_in[7 + i * 4 + 2];
        bn_v[i] = (const float*)d_in[7 + i * 4 + 3];
    }
    const float* wlin = (const float*)d_in[31];
    float* out = (float*)d_out;

    char* ws = (char*)d_ws;
    auto alloc = [&](size_t bytes) {
        char* p = ws;
        ws += (bytes + 255) & ~(size_t)255;
        return p;
    };
    uint32_t* pw2 = (uint32_t*)alloc((size_t)9 * 12 * 384 * 4);
    uint32_t* pw3 = (uint32_t*)alloc((size_t)9 * 12 * 768 * 4);
    uint32_t* pw4 = (uint32_t*)alloc((size_t)9 * 24 * 768 * 4);
    uint32_t* pw5 = (uint32_t*)alloc((size_t)9 * 24 * 1536 * 4);
    uint32_t* pw6 = (uint32_t*)alloc((size_t)9 * 48 * 512 * 4);
    int* wp2 = (int*)alloc((size_t)9 * 384 * 4);
    int* wp3 = (int*)alloc((size_t)9 * 768 * 4);
    int* wp4 = (int*)alloc((size_t)9 * 768 * 4);
    int* wp5 = (int*)alloc((size_t)9 * 1536 * 4);
    int* wp6 = (int*)alloc((size_t)9 * 512 * 4);
    uint32_t* s1 = (uint32_t*)alloc((size_t)128 * 32 * 12 * 32 * 4);
    uint32_t* s2 = (uint32_t*)alloc((size_t)128 * 16 * 12 * 16 * 4);
    uint32_t* s3 = (uint32_t*)alloc((size_t)128 * 16 * 24 * 16 * 4);
    uint32_t* s4 = (uint32_t*)alloc((size_t)128 * 8 * 24 * 8 * 4);
    uint32_t* s5 = (uint32_t*)alloc((size_t)128 * 8 * 48 * 8 * 4);
    float*    h6 = (float*)alloc((size_t)128 * 512 * 16 * 4);

    // pack binarized weights + per-tap popcounts
    {
        int t2 = 9 * 12 * 384, t3 = 9 * 12 * 768, t4 = 9 * 24 * 768,
            t5 = 9 * 24 * 1536, t6 = 9 * 48 * 512;
        pack_w2_kernel<<<(t2 + 255) / 256, 256, 0, stream>>>(w2, pw2, 384, 384);
        pack_w2_kernel<<<(t3 + 255) / 256, 256, 0, stream>>>(w3, pw3, 768, 384);
        pack_w2_kernel<<<(t4 + 255) / 256, 256, 0, stream>>>(w4, pw4, 768, 768);
        pack_w2_kernel<<<(t5 + 255) / 256, 256, 0, stream>>>(w5, pw5, 1536, 768);
        pack_w2_kernel<<<(t6 + 255) / 256, 256, 0, stream>>>(w6, pw6, 512, 1536);
        wpop_kernel<<<(9 * 384 + 255) / 256, 256, 0, stream>>>(pw2, wp2, 384, 12);
        wpop_kernel<<<(9 * 768 + 255) / 256, 256, 0, stream>>>(pw3, wp3, 768, 12);
        wpop_kernel<<<(9 * 768 + 255) / 256, 256, 0, stream>>>(pw4, wp4, 768, 24);
        wpop_kernel<<<(9 * 1536 + 255) / 256, 256, 0, stream>>>(pw5, wp5, 1536, 24);
        wpop_kernel<<<(9 * 512 + 255) / 256, 256, 0, stream>>>(pw6, wp6, 512, 48);
    }

    // block 1: fp32 conv + BN + sign-pack
    conv1_pack_kernel<<<128 * 32, 384, 0, stream>>>(
        x, w1, bn_g[0], bn_b[0], bn_m[0], bn_v[0], s1);

    // block 2: 384->384 @32x32 +pool   (grid 128*16, block 384)
    bconv2_kernel<12, 32, true, false, 384, 4><<<128 * 16, 384, 0, stream>>>(
        s1, pw2, wp2, bn_g[1], bn_b[1], bn_m[1], bn_v[1], s2, nullptr, 128, 384);
    // block 3: 384->768 @16x16         (grid 128*16, block 768)
    bconv2_kernel<12, 16, false, false, 768, 8><<<128 * 16, 768, 0, stream>>>(
        s2, pw3, wp3, bn_g[2], bn_b[2], bn_m[2], bn_v[2], s3, nullptr, 128, 768);
    // block 4: 768->768 @16x16 +pool   (grid 128*8, block 768)
    bconv2_kernel<24, 16, true, false, 768, 4><<<128 * 8, 768, 0, stream>>>(
        s3, pw4, wp4, bn_g[3], bn_b[3], bn_m[3], bn_v[3], s4, nullptr, 128, 768);
    // block 5: 768->1536 @8x8          (grid 128*8*2, block 768)
    bconv2_kernel<24, 8, false, false, 768, 8><<<128 * 8 * 2, 768, 0, stream>>>(
        s4, pw5, wp5, bn_g[4], bn_b[4], bn_m[4], bn_v[4], s5, nullptr, 128, 1536);
    // block 6: 1536->512 @8x8 +pool -> fp32 NCHW (grid 128*4, block 512)
    bconv2_kernel<48, 8, true, true, 512, 4><<<128 * 4, 512, 0, stream>>>(
        s5, pw6, wp6, bn_g[5], bn_b[5], bn_m[5], bn_v[5], nullptr, h6, 128, 512);

    // classifier + log_softmax
    classifier_kernel<<<128, 256, 0, stream>>>(h6, wlin, out);
}

// Round 3
// 1664.872 us; speedup vs baseline: 1.6419x; 1.0109x over previous
//
#include <hip/hip_runtime.h>
#include <stdint.h>

#define EPS 1e-5f

// ---------------------------------------------------------------------------
// conv1: full-precision 3->384 conv, 3x3 pad 1, fused BN+sign, bit-packed out
// s1[n][y][cog(12)][x], bit = co&31.  block=384 (x:32, cog:12), grid=128*32
// ---------------------------------------------------------------------------
__global__ void conv1_pack_kernel(const float* __restrict__ x,
                                  const float* __restrict__ w1,
                                  const float* __restrict__ g,
                                  const float* __restrict__ b,
                                  const float* __restrict__ m,
                                  const float* __restrict__ v,
                                  uint32_t* __restrict__ out)
{
    int bid = blockIdx.x;
    int n = bid >> 5;
    int y = bid & 31;
    int tid = threadIdx.x;
    int xo = tid & 31;
    int cog = tid >> 5;   // 0..11

    float a[27];
#pragma unroll
    for (int ci = 0; ci < 3; ++ci)
#pragma unroll
        for (int dy = 0; dy < 3; ++dy)
#pragma unroll
            for (int dx = 0; dx < 3; ++dx) {
                int yy = y + dy - 1, xx = xo + dx - 1;
                float val = 0.f;
                if (yy >= 0 && yy < 32 && xx >= 0 && xx < 32)
                    val = x[((n * 3 + ci) * 32 + yy) * 32 + xx];
                a[(ci * 3 + dy) * 3 + dx] = val;
            }

    uint32_t word = 0;
    for (int cs = 0; cs < 32; ++cs) {
        int co = cog * 32 + cs;
        const float* wp = w1 + co * 27;
        float acc = 0.f;
#pragma unroll
        for (int i = 0; i < 27; ++i) acc += a[i] * wp[i];
        float t = (acc - m[co]) * (g[co] * rsqrtf(v[co] + EPS)) + b[co];
        word |= (uint32_t)(t >= 0.f) << cs;
    }
    out[((n * 32 + y) * 12 + cog) * 32 + xo] = word;
}

// ---------------------------------------------------------------------------
// binarize + bit-pack weights: out[(tap*CW + cw)*Co + co], bit = ci&31
// ---------------------------------------------------------------------------
__global__ void pack_w2_kernel(const float* __restrict__ w,
                               uint32_t* __restrict__ out,
                               int Co, int Ci)
{
    int CW = Ci >> 5;
    int idx = blockIdx.x * 256 + threadIdx.x;
    int total = 9 * CW * Co;
    if (idx >= total) return;
    int co  = idx % Co;
    int cw  = (idx / Co) % CW;
    int tap = idx / (Co * CW);
    uint32_t word = 0;
    for (int bit = 0; bit < 32; ++bit) {
        float wv = w[(long)co * Ci * 9 + (cw * 32 + bit) * 9 + tap];
        word |= (uint32_t)(wv >= 0.f) << bit;
    }
    out[idx] = word;
}

// wpop[tap*Co + co] = sum_cw popc(w) — for zero-pad boundary correction
__global__ void wpop_kernel(const uint32_t* __restrict__ pw,
                            int* __restrict__ wpop, int Co, int CW)
{
    int idx = blockIdx.x * 256 + threadIdx.x;
    if (idx >= 9 * Co) return;
    int co = idx % Co, tap = idx / Co;
    int s = 0;
    for (int cw = 0; cw < CW; ++cw) s += __popc(pw[(tap * CW + cw) * Co + co]);
    wpop[idx] = s;
}

// ---------------------------------------------------------------------------
// bconv2: binary conv 3x3 pad1 (+opt 2x2 maxpool) + BN + (sign-pack|hardtanh)
// thread = one output channel; block = COB channels for one (n, yo) out row.
// act:  [N][Hin][CWIN][Win] packed words (bit = ci&31), staged in LDS w/ halo
// wgt:  [9][CWIN][Co] (co fastest -> coalesced per-lane loads)
// aout: [N][Ho][CWo][Wo] (bit = co&31) via __ballot
// fout: [N][Co][Ho][Wo] fp32 hardtanh
// __launch_bounds__(COB, 2): cap occupancy target so the register allocator
// can keep the act window + weights + counters live (40-VGPR starvation at
// default bounds caused LDS re-reads: R1 post-mortem).
// ---------------------------------------------------------------------------
template<int CWIN, int WIN, bool POOL, bool OUTF32, int COB, int XT>
__global__ __launch_bounds__(COB, 2) void bconv2_kernel(
    const uint32_t* __restrict__ act,
    const uint32_t* __restrict__ wgt,
    const int* __restrict__ wpop,
    const float* __restrict__ g, const float* __restrict__ b,
    const float* __restrict__ m, const float* __restrict__ v,
    uint32_t* __restrict__ aout, float* __restrict__ fout,
    int N, int Co)
{
    constexpr int HIN = WIN;
    constexpr int HO = POOL ? WIN / 2 : WIN;
    constexpr int WO = HO;
    constexpr int ROWS = POOL ? 4 : 3;
    constexpr int LW = WIN + 2;
    constexpr int PSUB = POOL ? 2 : 1;   // subpixel rows/cols per output pixel
    constexpr int NC = XT * PSUB;        // accumulator columns (input cols)
    constexpr int SPAN = NC + 2;

    __shared__ uint32_t lds[ROWS][CWIN][LW];

    const int cbn = Co / COB;
    int bid = blockIdx.x;
    int cb = bid % cbn;
    int yo = (bid / cbn) % HO;
    int n  = bid / (cbn * HO);
    int tid = threadIdx.x;

    // stage act rows (zero-padded halo)
    {
        int total = ROWS * CWIN * LW;
        int y0 = POOL ? (2 * yo - 1) : (yo - 1);
        for (int idx = tid; idx < total; idx += COB) {
            int xp = idx % LW;
            int cw = (idx / LW) % CWIN;
            int r  = idx / (LW * CWIN);
            int xg = xp - 1;
            int yg = y0 + r;
            uint32_t val = 0;
            if (xg >= 0 && xg < WIN && yg >= 0 && yg < HIN)
                val = act[((n * HIN + yg) * CWIN + cw) * WIN + xg];
            (&lds[0][0][0])[idx] = val;
        }
    }
    __syncthreads();

    int co = cb * COB + tid;
    float scale = g[co] * rsqrtf(v[co] + EPS);
    float mean = m[co], beta = b[co];

    int wp9[9];
#pragma unroll
    for (int t9 = 0; t9 < 9; ++t9) wp9[t9] = wpop[t9 * Co + co];

    int py0 = POOL ? 2 * yo : yo;
    bool rowlo = (py0 == 0);
    bool rowhi = (py0 + PSUB - 1 == HIN - 1);

    for (int xo0 = 0; xo0 < WO; xo0 += XT) {
        int cnt[PSUB][NC];
#pragma unroll
        for (int p = 0; p < PSUB; ++p)
#pragma unroll
            for (int c = 0; c < NC; ++c) cnt[p][c] = 0;

        int xb = xo0 * PSUB;   // lds col base (col j == input x j-1 ... halo)

        for (int cw = 0; cw < CWIN; ++cw) {
            uint32_t wv[9];
#pragma unroll
            for (int t9 = 0; t9 < 9; ++t9)
                wv[t9] = wgt[(t9 * CWIN + cw) * Co + co];
#pragma unroll
            for (int r = 0; r < ROWS; ++r) {
                uint32_t aw[SPAN];
#pragma unroll
                for (int j = 0; j < SPAN; ++j) aw[j] = lds[r][cw][xb + j];
#pragma unroll
                for (int p = 0; p < PSUB; ++p) {
                    int dy = r - p;
                    if (dy < 0 || dy > 2) continue;
#pragma unroll
                    for (int dx = 0; dx < 3; ++dx) {
                        uint32_t w = wv[dy * 3 + dx];
#pragma unroll
                        for (int c = 0; c < NC; ++c)
                            cnt[p][c] = __popc(aw[c + dx] ^ w) + cnt[p][c];
                    }
                }
            }
        }

        // epilogue: dot = 9*32*CWIN - 2*cnt - boundary corr; pool-max; BN
#pragma unroll
        for (int q = 0; q < XT; ++q) {
            int xo = xo0 + q;
            float best = -1e30f;
            constexpr int base9 = 9 * 32 * CWIN;
#pragma unroll
            for (int p = 0; p < PSUB; ++p)
#pragma unroll
                for (int cc = 0; cc < PSUB; ++cc) {
                    int c = q * PSUB + cc;
                    int px = xb + c;         // absolute input col
                    int dot = base9 - 2 * cnt[p][c];
                    bool plo = rowlo && (p == 0);
                    bool phi = rowhi && (p == PSUB - 1);
                    bool clo = (px == 0);
                    bool chi = (px == WIN - 1);
                    if (plo | phi | clo | chi) {
#pragma unroll
                        for (int dy = 0; dy < 3; ++dy)
#pragma unroll
                            for (int dx = 0; dx < 3; ++dx) {
                                bool inv = (dy == 0 && plo) || (dy == 2 && phi)
                                        || (dx == 0 && clo) || (dx == 2 && chi);
                                if (inv) dot -= 32 * CWIN - 2 * wp9[dy * 3 + dx];
                            }
                    }
                    float fv = (float)dot;
                    best = fmaxf(best, fv);
                }
            float t = (best - mean) * scale + beta;
            if (OUTF32) {
                float ht = fminf(1.f, fmaxf(-1.f, t));
                fout[(((long)n * Co + co) * HO + yo) * WO + xo] = ht;
            } else {
                unsigned long long mask = __ballot(t >= 0.f);
                int lane = tid & 63;
                if ((lane & 31) == 0) {
                    uint32_t wrd = (uint32_t)(mask >> (lane & 32));
                    int cog = co >> 5;
                    aout[((n * HO + yo) * (Co >> 5) + cog) * WO + xo] = wrd;
                }
            }
        }
    }
}

// ---------------------------------------------------------------------------
// classifier: logits = h @ w_lin.T (128 x 8192 x 10) then log_softmax
// ---------------------------------------------------------------------------
__global__ void classifier_kernel(const float* __restrict__ h,
                                  const float* __restrict__ wl,
                                  float* __restrict__ out)
{
    int n = blockIdx.x;
    int tid = threadIdx.x;
    float acc[10];
#pragma unroll
    for (int j = 0; j < 10; ++j) acc[j] = 0.f;
    for (int k = tid; k < 8192; k += 256) {
        float hv = h[n * 8192 + k];
#pragma unroll
        for (int j = 0; j < 10; ++j) acc[j] += hv * wl[j * 8192 + k];
    }
    __shared__ float sred[256];
    __shared__ float logit[10];
    for (int j = 0; j < 10; ++j) {
        sred[tid] = acc[j];
        __syncthreads();
        for (int s = 128; s > 0; s >>= 1) {
            if (tid < s) sred[tid] += sred[tid + s];
            __syncthreads();
        }
        if (tid == 0) logit[j] = sred[0];
        __syncthreads();
    }
    if (tid == 0) {
        float mx = logit[0];
#pragma unroll
        for (int j = 1; j < 10; ++j) mx = fmaxf(mx, logit[j]);
        float s = 0.f;
#pragma unroll
        for (int j = 0; j < 10; ++j) s += expf(logit[j] - mx);
        float lse = logf(s) + mx;
#pragma unroll
        for (int j = 0; j < 10; ++j) out[n * 10 + j] = logit[j] - lse;
    }
}

// ---------------------------------------------------------------------------
extern "C" void kernel_launch(void* const* d_in, const int* in_sizes, int n_in,
                              void* d_out, int out_size, void* d_ws, size_t ws_size,
                              hipStream_t stream)
{
    const float* x    = (const float*)d_in[0];
    const float* w1   = (const float*)d_in[1];
    const float* w2   = (const float*)d_in[2];
    const float* w3   = (const float*)d_in[3];
    const float* w4   = (const float*)d_in[4];
    const float* w5   = (const float*)d_in[5];
    const float* w6   = (const float*)d_in[6];
    const float* bn_g[6], *bn_b[6], *bn_m[6], *bn_v[6];
    for (int i = 0; i < 6; ++i) {
        bn_g[i] = (const float*)d_in[7 + i * 4 + 0];
        bn_b[i] = (const float*)d_in[7 + i * 4 + 1];
        bn_m[i] = (const float*)d_in[7 + i * 4 + 2];
        bn_v[i] = (const float*)d_in[7 + i * 4 + 3];
    }
    const float* wlin = (const float*)d_in[31];
    float* out = (float*)d_out;

    char* ws = (char*)d_ws;
    auto alloc = [&](size_t bytes) {
        char* p = ws;
        ws += (bytes + 255) & ~(size_t)255;
        return p;
    };
    uint32_t* pw2 = (uint32_t*)alloc((size_t)9 * 12 * 384 * 4);
    uint32_t* pw3 = (uint32_t*)alloc((size_t)9 * 12 * 768 * 4);
    uint32_t* pw4 = (uint32_t*)alloc((size_t)9 * 24 * 768 * 4);
    uint32_t* pw5 = (uint32_t*)alloc((size_t)9 * 24 * 1536 * 4);
    uint32_t* pw6 = (uint32_t*)alloc((size_t)9 * 48 * 512 * 4);
    int* wp2 = (int*)alloc((size_t)9 * 384 * 4);
    int* wp3 = (int*)alloc((size_t)9 * 768 * 4);
    int* wp4 = (int*)alloc((size_t)9 * 768 * 4);
    int* wp5 = (int*)alloc((size_t)9 * 1536 * 4);
    int* wp6 = (int*)alloc((size_t)9 * 512 * 4);
    uint32_t* s1 = (uint32_t*)alloc((size_t)128 * 32 * 12 * 32 * 4);
    uint32_t* s2 = (uint32_t*)alloc((size_t)128 * 16 * 12 * 16 * 4);
    uint32_t* s3 = (uint32_t*)alloc((size_t)128 * 16 * 24 * 16 * 4);
    uint32_t* s4 = (uint32_t*)alloc((size_t)128 * 8 * 24 * 8 * 4);
    uint32_t* s5 = (uint32_t*)alloc((size_t)128 * 8 * 48 * 8 * 4);
    float*    h6 = (float*)alloc((size_t)128 * 512 * 16 * 4);

    // pack binarized weights + per-tap popcounts
    {
        int t2 = 9 * 12 * 384, t3 = 9 * 12 * 768, t4 = 9 * 24 * 768,
            t5 = 9 * 24 * 1536, t6 = 9 * 48 * 512;
        pack_w2_kernel<<<(t2 + 255) / 256, 256, 0, stream>>>(w2, pw2, 384, 384);
        pack_w2_kernel<<<(t3 + 255) / 256, 256, 0, stream>>>(w3, pw3, 768, 384);
        pack_w2_kernel<<<(t4 + 255) / 256, 256, 0, stream>>>(w4, pw4, 768, 768);
        pack_w2_kernel<<<(t5 + 255) / 256, 256, 0, stream>>>(w5, pw5, 1536, 768);
        pack_w2_kernel<<<(t6 + 255) / 256, 256, 0, stream>>>(w6, pw6, 512, 1536);
        wpop_kernel<<<(9 * 384 + 255) / 256, 256, 0, stream>>>(pw2, wp2, 384, 12);
        wpop_kernel<<<(9 * 768 + 255) / 256, 256, 0, stream>>>(pw3, wp3, 768, 12);
        wpop_kernel<<<(9 * 768 + 255) / 256, 256, 0, stream>>>(pw4, wp4, 768, 24);
        wpop_kernel<<<(9 * 1536 + 255) / 256, 256, 0, stream>>>(pw5, wp5, 1536, 24);
        wpop_kernel<<<(9 * 512 + 255) / 256, 256, 0, stream>>>(pw6, wp6, 512, 48);
    }

    // block 1: fp32 conv + BN + sign-pack
    conv1_pack_kernel<<<128 * 32, 384, 0, stream>>>(
        x, w1, bn_g[0], bn_b[0], bn_m[0], bn_v[0], s1);

    // block 2: 384->384 @32x32 +pool   (grid 128*16, block 384)
    bconv2_kernel<12, 32, true, false, 384, 8><<<128 * 16, 384, 0, stream>>>(
        s1, pw2, wp2, bn_g[1], bn_b[1], bn_m[1], bn_v[1], s2, nullptr, 128, 384);
    // block 3: 384->768 @16x16         (grid 128*16, block 768)
    bconv2_kernel<12, 16, false, false, 768, 16><<<128 * 16, 768, 0, stream>>>(
        s2, pw3, wp3, bn_g[2], bn_b[2], bn_m[2], bn_v[2], s3, nullptr, 128, 768);
    // block 4: 768->768 @16x16 +pool   (grid 128*8, block 768)
    bconv2_kernel<24, 16, true, false, 768, 4><<<128 * 8, 768, 0, stream>>>(
        s3, pw4, wp4, bn_g[3], bn_b[3], bn_m[3], bn_v[3], s4, nullptr, 128, 768);
    // block 5: 768->1536 @8x8          (grid 128*8*2, block 768)
    bconv2_kernel<24, 8, false, false, 768, 8><<<128 * 8 * 2, 768, 0, stream>>>(
        s4, pw5, wp5, bn_g[4], bn_b[4], bn_m[4], bn_v[4], s5, nullptr, 128, 1536);
    // block 6: 1536->512 @8x8 +pool -> fp32 NCHW (grid 128*4, block 512)
    bconv2_kernel<48, 8, true, true, 512, 4><<<128 * 4, 512, 0, stream>>>(
        s5, pw6, wp6, bn_g[5], bn_b[5], bn_m[5], bn_v[5], nullptr, h6, 128, 512);

    // classifier + log_softmax
    classifier_kernel<<<128, 256, 0, stream>>>(h6, wlin, out);
}

// Round 4
// 1456.036 us; speedup vs baseline: 1.8774x; 1.1434x over previous
//
#include <hip/hip_runtime.h>
#include <stdint.h>

#define EPS 1e-5f

// pinned 2-op inner step: v_xor_b32 + accumulating v_bcnt_u32_b32
__device__ __forceinline__ int xorpop(uint32_t a, uint32_t w, int c)
{
    uint32_t t = a ^ w;
    asm("v_bcnt_u32_b32 %0, %1, %0" : "+v"(c) : "v"(t));
    return c;
}

// ---------------------------------------------------------------------------
// conv1: full-precision 3->384 conv, 3x3 pad 1, fused BN+sign, bit-packed out
// s1[n][y][cog(12)][x], bit = co&31.  block=384 (x:32, cog:12), grid=128*32
// ---------------------------------------------------------------------------
__global__ void conv1_pack_kernel(const float* __restrict__ x,
                                  const float* __restrict__ w1,
                                  const float* __restrict__ g,
                                  const float* __restrict__ b,
                                  const float* __restrict__ m,
                                  const float* __restrict__ v,
                                  uint32_t* __restrict__ out)
{
    int bid = blockIdx.x;
    int n = bid >> 5;
    int y = bid & 31;
    int tid = threadIdx.x;
    int xo = tid & 31;
    int cog = tid >> 5;   // 0..11

    float a[27];
#pragma unroll
    for (int ci = 0; ci < 3; ++ci)
#pragma unroll
        for (int dy = 0; dy < 3; ++dy)
#pragma unroll
            for (int dx = 0; dx < 3; ++dx) {
                int yy = y + dy - 1, xx = xo + dx - 1;
                float val = 0.f;
                if (yy >= 0 && yy < 32 && xx >= 0 && xx < 32)
                    val = x[((n * 3 + ci) * 32 + yy) * 32 + xx];
                a[(ci * 3 + dy) * 3 + dx] = val;
            }

    uint32_t word = 0;
    for (int cs = 0; cs < 32; ++cs) {
        int co = cog * 32 + cs;
        const float* wp = w1 + co * 27;
        float acc = 0.f;
#pragma unroll
        for (int i = 0; i < 27; ++i) acc += a[i] * wp[i];
        float t = (acc - m[co]) * (g[co] * rsqrtf(v[co] + EPS)) + b[co];
        word |= (uint32_t)(t >= 0.f) << cs;
    }
    out[((n * 32 + y) * 12 + cog) * 32 + xo] = word;
}

// ---------------------------------------------------------------------------
// binarize + bit-pack weights: out[(tap*CW + cw)*Co + co], bit = ci&31
// ---------------------------------------------------------------------------
__global__ void pack_w2_kernel(const float* __restrict__ w,
                               uint32_t* __restrict__ out,
                               int Co, int Ci)
{
    int CW = Ci >> 5;
    int idx = blockIdx.x * 256 + threadIdx.x;
    int total = 9 * CW * Co;
    if (idx >= total) return;
    int co  = idx % Co;
    int cw  = (idx / Co) % CW;
    int tap = idx / (Co * CW);
    uint32_t word = 0;
    for (int bit = 0; bit < 32; ++bit) {
        float wv = w[(long)co * Ci * 9 + (cw * 32 + bit) * 9 + tap];
        word |= (uint32_t)(wv >= 0.f) << bit;
    }
    out[idx] = word;
}

// wpop[tap*Co + co] = sum_cw popc(w) — for zero-pad boundary correction
__global__ void wpop_kernel(const uint32_t* __restrict__ pw,
                            int* __restrict__ wpop, int Co, int CW)
{
    int idx = blockIdx.x * 256 + threadIdx.x;
    if (idx >= 9 * Co) return;
    int co = idx % Co, tap = idx / Co;
    int s = 0;
    for (int cw = 0; cw < CW; ++cw) s += __popc(pw[(tap * CW + cw) * Co + co]);
    wpop[idx] = s;
}

// ---------------------------------------------------------------------------
// bconv2: binary conv 3x3 pad1 (+opt 2x2 maxpool) + BN + (sign-pack|hardtanh)
// thread = one output channel; block = COB channels for one (n, yo) out row.
// act:  [N][Hin][CWIN][Win] packed words (bit = ci&31), staged in LDS w/ halo
// wgt:  [9][CWIN][Co] (co fastest -> coalesced per-lane loads)
// aout: [N][Ho][CWo][Wo] (bit = co&31) via __ballot
// fout: [N][Co][Ho][Wo] fp32 hardtanh
// XT = full output row: weights loaded once per thread; inner 32-MAC step
// pinned to v_xor_b32 + v_bcnt_u32_b32(accum) via xorpop().
// ---------------------------------------------------------------------------
template<int CWIN, int WIN, bool POOL, bool OUTF32, int COB, int XT>
__global__ __launch_bounds__(COB, 2) void bconv2_kernel(
    const uint32_t* __restrict__ act,
    const uint32_t* __restrict__ wgt,
    const int* __restrict__ wpop,
    const float* __restrict__ g, const float* __restrict__ b,
    const float* __restrict__ m, const float* __restrict__ v,
    uint32_t* __restrict__ aout, float* __restrict__ fout,
    int N, int Co)
{
    constexpr int HIN = WIN;
    constexpr int HO = POOL ? WIN / 2 : WIN;
    constexpr int WO = HO;
    constexpr int ROWS = POOL ? 4 : 3;
    constexpr int LW = WIN + 2;
    constexpr int PSUB = POOL ? 2 : 1;   // subpixel rows/cols per output pixel
    constexpr int NC = XT * PSUB;        // accumulator columns (input cols)
    constexpr int SPAN = NC + 2;

    __shared__ uint32_t lds[ROWS][CWIN][LW];

    const int cbn = Co / COB;
    int bid = blockIdx.x;
    int cb = bid % cbn;
    int yo = (bid / cbn) % HO;
    int n  = bid / (cbn * HO);
    int tid = threadIdx.x;

    // stage act rows (zero-padded halo)
    {
        int total = ROWS * CWIN * LW;
        int y0 = POOL ? (2 * yo - 1) : (yo - 1);
        for (int idx = tid; idx < total; idx += COB) {
            int xp = idx % LW;
            int cw = (idx / LW) % CWIN;
            int r  = idx / (LW * CWIN);
            int xg = xp - 1;
            int yg = y0 + r;
            uint32_t val = 0;
            if (xg >= 0 && xg < WIN && yg >= 0 && yg < HIN)
                val = act[((n * HIN + yg) * CWIN + cw) * WIN + xg];
            (&lds[0][0][0])[idx] = val;
        }
    }
    __syncthreads();

    int co = cb * COB + tid;
    float scale = g[co] * rsqrtf(v[co] + EPS);
    float mean = m[co], beta = b[co];

    int wp9[9];
#pragma unroll
    for (int t9 = 0; t9 < 9; ++t9) wp9[t9] = wpop[t9 * Co + co];

    int py0 = POOL ? 2 * yo : yo;
    bool rowlo = (py0 == 0);
    bool rowhi = (py0 + PSUB - 1 == HIN - 1);

    for (int xo0 = 0; xo0 < WO; xo0 += XT) {
        int cnt[PSUB][NC];
#pragma unroll
        for (int p = 0; p < PSUB; ++p)
#pragma unroll
            for (int c = 0; c < NC; ++c) cnt[p][c] = 0;

        int xb = xo0 * PSUB;   // lds col base (col j == input x j-1 ... halo)

        for (int cw = 0; cw < CWIN; ++cw) {
            uint32_t wv[9];
#pragma unroll
            for (int t9 = 0; t9 < 9; ++t9)
                wv[t9] = wgt[(t9 * CWIN + cw) * Co + co];
#pragma unroll
            for (int r = 0; r < ROWS; ++r) {
                uint32_t aw[SPAN];
#pragma unroll
                for (int j = 0; j < SPAN; ++j) aw[j] = lds[r][cw][xb + j];
#pragma unroll
                for (int p = 0; p < PSUB; ++p) {
                    int dy = r - p;
                    if (dy < 0 || dy > 2) continue;
#pragma unroll
                    for (int dx = 0; dx < 3; ++dx) {
                        uint32_t w = wv[dy * 3 + dx];
#pragma unroll
                        for (int c = 0; c < NC; ++c)
                            cnt[p][c] = xorpop(aw[c + dx], w, cnt[p][c]);
                    }
                }
            }
        }

        // epilogue: dot = 9*32*CWIN - 2*cnt - boundary corr; pool-max; BN
#pragma unroll
        for (int q = 0; q < XT; ++q) {
            int xo = xo0 + q;
            float best = -1e30f;
            constexpr int base9 = 9 * 32 * CWIN;
#pragma unroll
            for (int p = 0; p < PSUB; ++p)
#pragma unroll
                for (int cc = 0; cc < PSUB; ++cc) {
                    int c = q * PSUB + cc;
                    int px = xb + c;         // absolute input col
                    int dot = base9 - 2 * cnt[p][c];
                    bool plo = rowlo && (p == 0);
                    bool phi = rowhi && (p == PSUB - 1);
                    bool clo = (px == 0);
                    bool chi = (px == WIN - 1);
                    if (plo | phi | clo | chi) {
#pragma unroll
                        for (int dy = 0; dy < 3; ++dy)
#pragma unroll
                            for (int dx = 0; dx < 3; ++dx) {
                                bool inv = (dy == 0 && plo) || (dy == 2 && phi)
                                        || (dx == 0 && clo) || (dx == 2 && chi);
                                if (inv) dot -= 32 * CWIN - 2 * wp9[dy * 3 + dx];
                            }
                    }
                    float fv = (float)dot;
                    best = fmaxf(best, fv);
                }
            float t = (best - mean) * scale + beta;
            if (OUTF32) {
                float ht = fminf(1.f, fmaxf(-1.f, t));
                fout[(((long)n * Co + co) * HO + yo) * WO + xo] = ht;
            } else {
                unsigned long long mask = __ballot(t >= 0.f);
                int lane = tid & 63;
                if ((lane & 31) == 0) {
                    uint32_t wrd = (uint32_t)(mask >> (lane & 32));
                    int cog = co >> 5;
                    aout[((n * HO + yo) * (Co >> 5) + cog) * WO + xo] = wrd;
                }
            }
        }
    }
}

// ---------------------------------------------------------------------------
// classifier: logits = h @ w_lin.T (128 x 8192 x 10) then log_softmax
// ---------------------------------------------------------------------------
__global__ void classifier_kernel(const float* __restrict__ h,
                                  const float* __restrict__ wl,
                                  float* __restrict__ out)
{
    int n = blockIdx.x;
    int tid = threadIdx.x;
    float acc[10];
#pragma unroll
    for (int j = 0; j < 10; ++j) acc[j] = 0.f;
    for (int k = tid; k < 8192; k += 256) {
        float hv = h[n * 8192 + k];
#pragma unroll
        for (int j = 0; j < 10; ++j) acc[j] += hv * wl[j * 8192 + k];
    }
    __shared__ float sred[256];
    __shared__ float logit[10];
    for (int j = 0; j < 10; ++j) {
        sred[tid] = acc[j];
        __syncthreads();
        for (int s = 128; s > 0; s >>= 1) {
            if (tid < s) sred[tid] += sred[tid + s];
            __syncthreads();
        }
        if (tid == 0) logit[j] = sred[0];
        __syncthreads();
    }
    if (tid == 0) {
        float mx = logit[0];
#pragma unroll
        for (int j = 1; j < 10; ++j) mx = fmaxf(mx, logit[j]);
        float s = 0.f;
#pragma unroll
        for (int j = 0; j < 10; ++j) s += expf(logit[j] - mx);
        float lse = logf(s) + mx;
#pragma unroll
        for (int j = 0; j < 10; ++j) out[n * 10 + j] = logit[j] - lse;
    }
}

// ---------------------------------------------------------------------------
extern "C" void kernel_launch(void* const* d_in, const int* in_sizes, int n_in,
                              void* d_out, int out_size, void* d_ws, size_t ws_size,
                              hipStream_t stream)
{
    const float* x    = (const float*)d_in[0];
    const float* w1   = (const float*)d_in[1];
    const float* w2   = (const float*)d_in[2];
    const float* w3   = (const float*)d_in[3];
    const float* w4   = (const float*)d_in[4];
    const float* w5   = (const float*)d_in[5];
    const float* w6   = (const float*)d_in[6];
    const float* bn_g[6], *bn_b[6], *bn_m[6], *bn_v[6];
    for (int i = 0; i < 6; ++i) {
        bn_g[i] = (const float*)d_in[7 + i * 4 + 0];
        bn_b[i] = (const float*)d_in[7 + i * 4 + 1];
        bn_m[i] = (const float*)d_in[7 + i * 4 + 2];
        bn_v[i] = (const float*)d_in[7 + i * 4 + 3];
    }
    const float* wlin = (const float*)d_in[31];
    float* out = (float*)d_out;

    char* ws = (char*)d_ws;
    auto alloc = [&](size_t bytes) {
        char* p = ws;
        ws += (bytes + 255) & ~(size_t)255;
        return p;
    };
    uint32_t* pw2 = (uint32_t*)alloc((size_t)9 * 12 * 384 * 4);
    uint32_t* pw3 = (uint32_t*)alloc((size_t)9 * 12 * 768 * 4);
    uint32_t* pw4 = (uint32_t*)alloc((size_t)9 * 24 * 768 * 4);
    uint32_t* pw5 = (uint32_t*)alloc((size_t)9 * 24 * 1536 * 4);
    uint32_t* pw6 = (uint32_t*)alloc((size_t)9 * 48 * 512 * 4);
    int* wp2 = (int*)alloc((size_t)9 * 384 * 4);
    int* wp3 = (int*)alloc((size_t)9 * 768 * 4);
    int* wp4 = (int*)alloc((size_t)9 * 768 * 4);
    int* wp5 = (int*)alloc((size_t)9 * 1536 * 4);
    int* wp6 = (int*)alloc((size_t)9 * 512 * 4);
    uint32_t* s1 = (uint32_t*)alloc((size_t)128 * 32 * 12 * 32 * 4);
    uint32_t* s2 = (uint32_t*)alloc((size_t)128 * 16 * 12 * 16 * 4);
    uint32_t* s3 = (uint32_t*)alloc((size_t)128 * 16 * 24 * 16 * 4);
    uint32_t* s4 = (uint32_t*)alloc((size_t)128 * 8 * 24 * 8 * 4);
    uint32_t* s5 = (uint32_t*)alloc((size_t)128 * 8 * 48 * 8 * 4);
    float*    h6 = (float*)alloc((size_t)128 * 512 * 16 * 4);

    // pack binarized weights + per-tap popcounts
    {
        int t2 = 9 * 12 * 384, t3 = 9 * 12 * 768, t4 = 9 * 24 * 768,
            t5 = 9 * 24 * 1536, t6 = 9 * 48 * 512;
        pack_w2_kernel<<<(t2 + 255) / 256, 256, 0, stream>>>(w2, pw2, 384, 384);
        pack_w2_kernel<<<(t3 + 255) / 256, 256, 0, stream>>>(w3, pw3, 768, 384);
        pack_w2_kernel<<<(t4 + 255) / 256, 256, 0, stream>>>(w4, pw4, 768, 768);
        pack_w2_kernel<<<(t5 + 255) / 256, 256, 0, stream>>>(w5, pw5, 1536, 768);
        pack_w2_kernel<<<(t6 + 255) / 256, 256, 0, stream>>>(w6, pw6, 512, 1536);
        wpop_kernel<<<(9 * 384 + 255) / 256, 256, 0, stream>>>(pw2, wp2, 384, 12);
        wpop_kernel<<<(9 * 768 + 255) / 256, 256, 0, stream>>>(pw3, wp3, 768, 12);
        wpop_kernel<<<(9 * 768 + 255) / 256, 256, 0, stream>>>(pw4, wp4, 768, 24);
        wpop_kernel<<<(9 * 1536 + 255) / 256, 256, 0, stream>>>(pw5, wp5, 1536, 24);
        wpop_kernel<<<(9 * 512 + 255) / 256, 256, 0, stream>>>(pw6, wp6, 512, 48);
    }

    // block 1: fp32 conv + BN + sign-pack
    conv1_pack_kernel<<<128 * 32, 384, 0, stream>>>(
        x, w1, bn_g[0], bn_b[0], bn_m[0], bn_v[0], s1);

    // block 2: 384->384 @32x32 +pool   (grid 128*16, block 384, full-row XT)
    bconv2_kernel<12, 32, true, false, 384, 16><<<128 * 16, 384, 0, stream>>>(
        s1, pw2, wp2, bn_g[1], bn_b[1], bn_m[1], bn_v[1], s2, nullptr, 128, 384);
    // block 3: 384->768 @16x16         (grid 128*16, block 768, full-row XT)
    bconv2_kernel<12, 16, false, false, 768, 16><<<128 * 16, 768, 0, stream>>>(
        s2, pw3, wp3, bn_g[2], bn_b[2], bn_m[2], bn_v[2], s3, nullptr, 128, 768);
    // block 4: 768->768 @16x16 +pool   (grid 128*8, block 768, full-row XT)
    bconv2_kernel<24, 16, true, false, 768, 8><<<128 * 8, 768, 0, stream>>>(
        s3, pw4, wp4, bn_g[3], bn_b[3], bn_m[3], bn_v[3], s4, nullptr, 128, 768);
    // block 5: 768->1536 @8x8          (grid 128*8*2, block 768)
    bconv2_kernel<24, 8, false, false, 768, 8><<<128 * 8 * 2, 768, 0, stream>>>(
        s4, pw5, wp5, bn_g[4], bn_b[4], bn_m[4], bn_v[4], s5, nullptr, 128, 1536);
    // block 6: 1536->512 @8x8 +pool -> fp32 NCHW (grid 128*4, block 512)
    bconv2_kernel<48, 8, true, true, 512, 4><<<128 * 4, 512, 0, stream>>>(
        s5, pw6, wp6, bn_g[5], bn_b[5], bn_m[5], bn_v[5], nullptr, h6, 128, 512);

    // classifier + log_softmax
    classifier_kernel<<<128, 256, 0, stream>>>(h6, wlin, out);
}